// Round 2
// baseline (354.418 us; speedup 1.0000x reference)
//
#include <hip/hip_runtime.h>

#define NND 8192
#define KNBR 8
#define DD 128
#define EPSF 1e-5f

// ---------------------------------------------------------------------------
// Degree / dinv: deg[i] = 1 (self) + #distinct valid neighbors != i.
// kept[i] bit j set iff neighbor j is valid, != i, and not a duplicate of an
// earlier valid neighbor. dinv = rsqrt(deg).
// ---------------------------------------------------------------------------
__global__ __launch_bounds__(256)
void deg_kernel(const int* __restrict__ neigh, const int* __restrict__ cnt,
                float* __restrict__ dinv, int* __restrict__ kept) {
    int i = blockIdx.x * 256 + threadIdx.x;
    if (i >= NND) return;
    int c = cnt[i];
    int nb[KNBR];
#pragma unroll
    for (int j = 0; j < KNBR; ++j) nb[j] = neigh[i * KNBR + j];
    int mask = 0, deg = 1;
#pragma unroll
    for (int j = 0; j < KNBR; ++j) {
        if (j < c) {
            int v = nb[j];
            bool dup = (v == i);
            for (int jj = 0; jj < j; ++jj)
                if (nb[jj] == v) { dup = true; }
            if (!dup) { mask |= (1 << j); deg++; }
        }
    }
    dinv[i] = rsqrtf((float)deg);
    kept[i] = mask;
}

// ---------------------------------------------------------------------------
// GEMM: out[m][o] (+)= sum_d A[m][d] * W[o][d]  (+ bias)  (opt relu)
// M=8192, N=128 (grid.y=2 halves of 64), K=128. W row stride = wStride.
// Block 256 thr: stages 64 rows x 128 cols of A into LDS (pad +1).
// Wave w handles cols [blockIdx.y*64 + w*16, +16) -> W index wave-uniform
// -> scalar loads. Lane = row within 64-row tile.
// ---------------------------------------------------------------------------
template <bool RELU, bool ACCUM>
__global__ __launch_bounds__(256)
void gemm_kernel(const float* __restrict__ A, const float* __restrict__ W,
                 int wStride, const float* __restrict__ bias,
                 float* __restrict__ out, int outStride, int outOffset) {
    __shared__ float sh[64 * 129];
    const int tid = threadIdx.x;
    const int rowBase = blockIdx.x * 64;
    const float* src = A + (size_t)rowBase * DD;
#pragma unroll
    for (int it = 0; it < 8; ++it) {
        int idx = tid + it * 256;        // 0..2047 float4 slots
        int m = idx >> 5;
        int d4 = idx & 31;
        float4 v = *reinterpret_cast<const float4*>(src + m * DD + d4 * 4);
        float* dst = &sh[m * 129 + d4 * 4];
        dst[0] = v.x; dst[1] = v.y; dst[2] = v.z; dst[3] = v.w;
    }
    __syncthreads();

    const int lane = tid & 63;
    const int w = __builtin_amdgcn_readfirstlane(tid >> 6);
    const int o0 = blockIdx.y * 64 + w * 16;

    float acc[16];
#pragma unroll
    for (int c = 0; c < 16; ++c) acc[c] = 0.f;

    const float* shrow = &sh[lane * 129];
    for (int d = 0; d < DD; d += 4) {
        float h0 = shrow[d], h1 = shrow[d + 1], h2 = shrow[d + 2], h3 = shrow[d + 3];
#pragma unroll
        for (int c = 0; c < 16; ++c) {
            const float4 wv =
                *reinterpret_cast<const float4*>(W + (size_t)(o0 + c) * wStride + d);
            acc[c] = fmaf(h0, wv.x, acc[c]);
            acc[c] = fmaf(h1, wv.y, acc[c]);
            acc[c] = fmaf(h2, wv.z, acc[c]);
            acc[c] = fmaf(h3, wv.w, acc[c]);
        }
    }

    const int row = rowBase + lane;
    float* orow = out + (size_t)row * outStride + outOffset + o0;
#pragma unroll
    for (int c4 = 0; c4 < 4; ++c4) {
        float4 v;
        if (ACCUM) {
            float4 prev = *reinterpret_cast<float4*>(orow + c4 * 4);
            v.x = prev.x + acc[c4 * 4 + 0];
            v.y = prev.y + acc[c4 * 4 + 1];
            v.z = prev.z + acc[c4 * 4 + 2];
            v.w = prev.w + acc[c4 * 4 + 3];
        } else {
            v.x = acc[c4 * 4 + 0] + bias[o0 + c4 * 4 + 0];
            v.y = acc[c4 * 4 + 1] + bias[o0 + c4 * 4 + 1];
            v.z = acc[c4 * 4 + 2] + bias[o0 + c4 * 4 + 2];
            v.w = acc[c4 * 4 + 3] + bias[o0 + c4 * 4 + 3];
        }
        if (RELU) {
            v.x = fmaxf(v.x, 0.f); v.y = fmaxf(v.y, 0.f);
            v.z = fmaxf(v.z, 0.f); v.w = fmaxf(v.w, 0.f);
        }
        *reinterpret_cast<float4*>(orow + c4 * 4) = v;
    }
}

__device__ __forceinline__ float wave_sum(float s) {
#pragma unroll
    for (int m = 1; m < 64; m <<= 1) s += __shfl_xor(s, m, 64);
    return s;
}

// ---------------------------------------------------------------------------
// GCN propagate + residual + LayerNorm. One wave per row, float2 per lane.
// h_out = LN( relu( dinv[i] * (dinv[i]*nxt[i] + sum_kept dinv[nb]*nxt[nb]) )
//             + resid[i] )
// ---------------------------------------------------------------------------
__global__ __launch_bounds__(256)
void prop_ln_kernel(const float* __restrict__ nxt, const float* __restrict__ resid,
                    const float* __restrict__ dinv, const int* __restrict__ kept,
                    const int* __restrict__ neigh,
                    const float* __restrict__ g, const float* __restrict__ b,
                    float* __restrict__ out, int outStride, int outOffset) {
    int row = blockIdx.x * 4 + (threadIdx.x >> 6);
    int lane = threadIdx.x & 63;
    const float2* nxt2 = (const float2*)nxt;
    float di = dinv[row];
    int km = kept[row];

    float2 self = nxt2[row * 64 + lane];
    float ax = di * self.x, ay = di * self.y;
#pragma unroll
    for (int j = 0; j < KNBR; ++j) {
        if (km & (1 << j)) {   // km is wave-uniform -> no divergence
            int nb = neigh[row * KNBR + j];
            float dn = dinv[nb];
            float2 v = nxt2[nb * 64 + lane];
            ax = fmaf(dn, v.x, ax);
            ay = fmaf(dn, v.y, ay);
        }
    }
    float2 r = ((const float2*)resid)[row * 64 + lane];
    float vx = fmaxf(di * ax, 0.f) + r.x;
    float vy = fmaxf(di * ay, 0.f) + r.y;

    float mu = wave_sum(vx + vy) * (1.f / 128.f);
    float dx = vx - mu, dy = vy - mu;
    float var = wave_sum(dx * dx + dy * dy) * (1.f / 128.f);
    float rs = rsqrtf(var + EPSF);

    float2 gg = ((const float2*)g)[lane];
    float2 bb = ((const float2*)b)[lane];
    float2 o;
    o.x = dx * rs * gg.x + bb.x;
    o.y = dy * rs * gg.y + bb.y;
    *reinterpret_cast<float2*>(out + (size_t)row * outStride + outOffset + lane * 2) = o;
}

// ---------------------------------------------------------------------------
// SAGE max-pool over first cnt neighbors (no dedupe, self allowed); 0 if cnt==0.
// ---------------------------------------------------------------------------
__global__ __launch_bounds__(256)
void pool_kernel(const float* __restrict__ enc, const int* __restrict__ neigh,
                 const int* __restrict__ cnt, float* __restrict__ out) {
    int row = blockIdx.x * 4 + (threadIdx.x >> 6);
    int lane = threadIdx.x & 63;
    int c = cnt[row];
    float2 acc = make_float2(0.f, 0.f);
    if (c > 0) {   // wave-uniform branch
        acc = make_float2(-1e30f, -1e30f);
        for (int j = 0; j < c; ++j) {
            int nb = neigh[row * KNBR + j];
            float2 v = ((const float2*)enc)[nb * 64 + lane];
            acc.x = fmaxf(acc.x, v.x);
            acc.y = fmaxf(acc.y, v.y);
        }
    }
    ((float2*)out)[row * 64 + lane] = acc;
}

// ---------------------------------------------------------------------------
// SAGE: s_new = LN(nxt + s_prev)
// ---------------------------------------------------------------------------
__global__ __launch_bounds__(256)
void add_ln_kernel(const float* __restrict__ nxt, const float* __restrict__ sprev,
                   const float* __restrict__ g, const float* __restrict__ b,
                   float* __restrict__ out, int outStride, int outOffset) {
    int row = blockIdx.x * 4 + (threadIdx.x >> 6);
    int lane = threadIdx.x & 63;
    float2 a = ((const float2*)nxt)[row * 64 + lane];
    float2 r = ((const float2*)sprev)[row * 64 + lane];
    float vx = a.x + r.x, vy = a.y + r.y;

    float mu = wave_sum(vx + vy) * (1.f / 128.f);
    float dx = vx - mu, dy = vy - mu;
    float var = wave_sum(dx * dx + dy * dy) * (1.f / 128.f);
    float rs = rsqrtf(var + EPSF);

    float2 gg = ((const float2*)g)[lane];
    float2 bb = ((const float2*)b)[lane];
    float2 o;
    o.x = dx * rs * gg.x + bb.x;
    o.y = dy * rs * gg.y + bb.y;
    *reinterpret_cast<float2*>(out + (size_t)row * outStride + outOffset + lane * 2) = o;
}

extern "C" void kernel_launch(void* const* d_in, const int* in_sizes, int n_in,
                              void* d_out, int out_size, void* d_ws, size_t ws_size,
                              hipStream_t stream) {
    (void)in_sizes; (void)n_in; (void)out_size; (void)ws_size;
    const float* x      = (const float*)d_in[0];
    const int*   neigh  = (const int*)d_in[1];
    const int*   cnt    = (const int*)d_in[2];
    const float* gcnW   = (const float*)d_in[3];
    const float* gcnB   = (const float*)d_in[4];
    const float* gcnG   = (const float*)d_in[5];
    const float* gcnBb  = (const float*)d_in[6];
    const float* poolW  = (const float*)d_in[7];
    const float* poolB  = (const float*)d_in[8];
    const float* mW     = (const float*)d_in[9];
    const float* mB     = (const float*)d_in[10];
    const float* sg     = (const float*)d_in[11];
    const float* sb     = (const float*)d_in[12];
    float* out = (float*)d_out;

    char* ws = (char*)d_ws;
    float* dinv = (float*)ws;                       // 8192 f
    int*   kept = (int*)(ws + 32 * 1024);           // 8192 i
    float* bufA = (float*)(ws + 64 * 1024);         // N*D
    float* bufB = bufA + NND * DD;
    float* bufC = bufB + NND * DD;

    dim3 blk(256);
    dim3 ggrid(NND / 64, 2);    // gemm
    dim3 rgrid(NND / 4);        // row-wise kernels

    deg_kernel<<<dim3(NND / 256), blk, 0, stream>>>(neigh, cnt, dinv, kept);

    // ---------------- GCN branch ----------------
    // layer 0: nxt0 = x@W0^T + b0 ; h1 = LN(relu(prop(nxt0)) + nxt0)
    gemm_kernel<false, false><<<ggrid, blk, 0, stream>>>(x, gcnW + 0 * DD * DD, DD,
                                                         gcnB + 0 * DD, bufA, DD, 0);
    prop_ln_kernel<<<rgrid, blk, 0, stream>>>(bufA, bufA, dinv, kept, neigh,
                                              gcnG + 0 * DD, gcnBb + 0 * DD, bufB, DD, 0);
    // layer 1
    gemm_kernel<false, false><<<ggrid, blk, 0, stream>>>(bufB, gcnW + 1 * DD * DD, DD,
                                                         gcnB + 1 * DD, bufA, DD, 0);
    prop_ln_kernel<<<rgrid, blk, 0, stream>>>(bufA, bufB, dinv, kept, neigh,
                                              gcnG + 1 * DD, gcnBb + 1 * DD, bufC, DD, 0);
    // layer 2 -> out cols [0,128)
    gemm_kernel<false, false><<<ggrid, blk, 0, stream>>>(bufC, gcnW + 2 * DD * DD, DD,
                                                         gcnB + 2 * DD, bufA, DD, 0);
    prop_ln_kernel<<<rgrid, blk, 0, stream>>>(bufA, bufC, dinv, kept, neigh,
                                              gcnG + 2 * DD, gcnBb + 2 * DD, out, 2 * DD, 0);

    // ---------------- SAGE branch ----------------
    // ne1 = relu(x@poolW^T + poolB)
    gemm_kernel<true, false><<<ggrid, blk, 0, stream>>>(x, poolW, DD, poolB, bufA, DD, 0);
    pool_kernel<<<rgrid, blk, 0, stream>>>(bufA, neigh, cnt, bufB);          // p1
    // s1 = relu(x@Wl0^T + p1@Wr0^T + b0)
    gemm_kernel<false, false><<<ggrid, blk, 0, stream>>>(x, mW + 0 * DD * 2 * DD, 2 * DD,
                                                         mB + 0 * DD, bufC, DD, 0);
    gemm_kernel<true, true><<<ggrid, blk, 0, stream>>>(bufB, mW + 0 * DD * 2 * DD + DD,
                                                       2 * DD, nullptr, bufC, DD, 0);
    // layer 1
    pool_kernel<<<rgrid, blk, 0, stream>>>(bufC, neigh, cnt, bufA);          // p2
    gemm_kernel<false, false><<<ggrid, blk, 0, stream>>>(bufC, mW + 1 * DD * 2 * DD, 2 * DD,
                                                         mB + 1 * DD, bufB, DD, 0);
    gemm_kernel<true, true><<<ggrid, blk, 0, stream>>>(bufA, mW + 1 * DD * 2 * DD + DD,
                                                       2 * DD, nullptr, bufB, DD, 0);
    add_ln_kernel<<<rgrid, blk, 0, stream>>>(bufB, bufC, sg + 0 * DD, sb + 0 * DD,
                                             bufA, DD, 0);                   // s2
    // layer 2 -> out cols [128,256)
    pool_kernel<<<rgrid, blk, 0, stream>>>(bufA, neigh, cnt, bufB);          // p3
    gemm_kernel<false, false><<<ggrid, blk, 0, stream>>>(bufA, mW + 2 * DD * 2 * DD, 2 * DD,
                                                         mB + 2 * DD, bufC, DD, 0);
    gemm_kernel<true, true><<<ggrid, blk, 0, stream>>>(bufB, mW + 2 * DD * 2 * DD + DD,
                                                       2 * DD, nullptr, bufC, DD, 0);
    add_ln_kernel<<<rgrid, blk, 0, stream>>>(bufC, bufA, sg + 1 * DD, sb + 1 * DD,
                                             out, 2 * DD, DD);
}

// Round 3
// 276.666 us; speedup vs baseline: 1.2810x; 1.2810x over previous
//
#include <hip/hip_runtime.h>

#define NND 8192
#define KNBR 8
#define DD 128
#define EPSF 1e-5f
#define SHSTRIDE 130   // 64x128 tile, +2 pad: float2 reads are 2-way aliased (free)

// ---------------------------------------------------------------------------
// Degree / dinv: deg[i] = 1 (self) + #distinct valid neighbors != i.
// kept[i] bit j set iff neighbor j valid, != i, not a dup of earlier neighbor.
// ---------------------------------------------------------------------------
__global__ __launch_bounds__(256)
void deg_kernel(const int* __restrict__ neigh, const int* __restrict__ cnt,
                float* __restrict__ dinv, int* __restrict__ kept) {
    int i = blockIdx.x * 256 + threadIdx.x;
    if (i >= NND) return;
    int c = cnt[i];
    int nb[KNBR];
#pragma unroll
    for (int j = 0; j < KNBR; ++j) nb[j] = neigh[i * KNBR + j];
    int mask = 0, deg = 1;
#pragma unroll
    for (int j = 0; j < KNBR; ++j) {
        if (j < c) {
            int v = nb[j];
            bool dup = (v == i);
            for (int jj = 0; jj < j; ++jj)
                if (nb[jj] == v) { dup = true; }
            if (!dup) { mask |= (1 << j); deg++; }
        }
    }
    dinv[i] = rsqrtf((float)deg);
    kept[i] = mask;
}

// ---------------------------------------------------------------------------
// Shared helpers for the rows-in-lanes GEMM.
// Block: 256 thr = 4 waves. Tile: 64 rows x 128 K staged in LDS.
// Wave w owns 4 output cols: o0 = blockIdx.y*16 + w*4  (grid.y = 8).
// W accesses are wave-uniform -> s_load_dwordx4; A row read as float2 from LDS.
// ---------------------------------------------------------------------------
__device__ __forceinline__ void stage_tile(float* sh, const float* __restrict__ src,
                                           int tid) {
#pragma unroll
    for (int it = 0; it < 8; ++it) {
        int idx = tid + it * 256;        // 2048 float4 slots: m=idx>>5, d4=idx&31
        int m = idx >> 5;
        int d4 = idx & 31;
        float4 v = *reinterpret_cast<const float4*>(src + m * DD + d4 * 4);
        float* dst = &sh[m * SHSTRIDE + d4 * 4];
        dst[0] = v.x; dst[1] = v.y; dst[2] = v.z; dst[3] = v.w;
    }
}

__device__ __forceinline__ void accum_tile(const float* sh, int lane,
                                           const float* __restrict__ Wbase,
                                           int wStride, int o0, float acc[4]) {
    const float* shrow = &sh[lane * SHSTRIDE];
    for (int d = 0; d < DD; d += 4) {
        float2 h01 = *reinterpret_cast<const float2*>(shrow + d);
        float2 h23 = *reinterpret_cast<const float2*>(shrow + d + 2);
#pragma unroll
        for (int c = 0; c < 4; ++c) {
            const float4 wv =
                *reinterpret_cast<const float4*>(Wbase + (size_t)(o0 + c) * wStride + d);
            acc[c] = fmaf(h01.x, wv.x, acc[c]);
            acc[c] = fmaf(h01.y, wv.y, acc[c]);
            acc[c] = fmaf(h23.x, wv.z, acc[c]);
            acc[c] = fmaf(h23.y, wv.w, acc[c]);
        }
    }
}

// out[m][o] = (relu?)(A @ W^T + bias), W row stride = DD
template <bool RELU>
__global__ __launch_bounds__(256)
void gemm_kernel(const float* __restrict__ A, const float* __restrict__ W,
                 const float* __restrict__ bias, float* __restrict__ out) {
    __shared__ float sh[64 * SHSTRIDE];
    const int tid = threadIdx.x;
    const int rowBase = blockIdx.x * 64;
    stage_tile(sh, A + (size_t)rowBase * DD, tid);
    __syncthreads();

    const int lane = tid & 63;
    const int w = __builtin_amdgcn_readfirstlane(tid >> 6);
    const int o0 = blockIdx.y * 16 + w * 4;
    float acc[4] = {0.f, 0.f, 0.f, 0.f};
    accum_tile(sh, lane, W, DD, o0, acc);

    float4 v;
    v.x = acc[0] + bias[o0 + 0];
    v.y = acc[1] + bias[o0 + 1];
    v.z = acc[2] + bias[o0 + 2];
    v.w = acc[3] + bias[o0 + 3];
    if (RELU) {
        v.x = fmaxf(v.x, 0.f); v.y = fmaxf(v.y, 0.f);
        v.z = fmaxf(v.z, 0.f); v.w = fmaxf(v.w, 0.f);
    }
    *reinterpret_cast<float4*>(out + (size_t)(rowBase + lane) * DD + o0) = v;
}

// out = relu([A1 | A2] @ W^T + bias), W is D x 2D row-major (stride 2D).
// Two-phase: stage A1, accumulate vs W[:, 0:D]; stage A2, accumulate vs W[:, D:2D].
__global__ __launch_bounds__(256)
void gemm2_kernel(const float* __restrict__ A1, const float* __restrict__ A2,
                  const float* __restrict__ W, const float* __restrict__ bias,
                  float* __restrict__ out) {
    __shared__ float sh[64 * SHSTRIDE];
    const int tid = threadIdx.x;
    const int rowBase = blockIdx.x * 64;
    const int lane = tid & 63;
    const int w = __builtin_amdgcn_readfirstlane(tid >> 6);
    const int o0 = blockIdx.y * 16 + w * 4;
    float acc[4] = {0.f, 0.f, 0.f, 0.f};

    stage_tile(sh, A1 + (size_t)rowBase * DD, tid);
    __syncthreads();
    accum_tile(sh, lane, W, 2 * DD, o0, acc);
    __syncthreads();
    stage_tile(sh, A2 + (size_t)rowBase * DD, tid);
    __syncthreads();
    accum_tile(sh, lane, W + DD, 2 * DD, o0, acc);

    float4 v;
    v.x = fmaxf(acc[0] + bias[o0 + 0], 0.f);
    v.y = fmaxf(acc[1] + bias[o0 + 1], 0.f);
    v.z = fmaxf(acc[2] + bias[o0 + 2], 0.f);
    v.w = fmaxf(acc[3] + bias[o0 + 3], 0.f);
    *reinterpret_cast<float4*>(out + (size_t)(rowBase + lane) * DD + o0) = v;
}

__device__ __forceinline__ float wave_sum(float s) {
#pragma unroll
    for (int m = 1; m < 64; m <<= 1) s += __shfl_xor(s, m, 64);
    return s;
}

// ---------------------------------------------------------------------------
// GCN propagate + residual + LayerNorm. One wave per row, float2 per lane.
// ---------------------------------------------------------------------------
__global__ __launch_bounds__(256)
void prop_ln_kernel(const float* __restrict__ nxt, const float* __restrict__ resid,
                    const float* __restrict__ dinv, const int* __restrict__ kept,
                    const int* __restrict__ neigh,
                    const float* __restrict__ g, const float* __restrict__ b,
                    float* __restrict__ out, int outStride, int outOffset) {
    int row = blockIdx.x * 4 + (threadIdx.x >> 6);
    int lane = threadIdx.x & 63;
    const float2* nxt2 = (const float2*)nxt;
    float di = dinv[row];
    int km = kept[row];

    float2 self = nxt2[row * 64 + lane];
    float ax = di * self.x, ay = di * self.y;
#pragma unroll
    for (int j = 0; j < KNBR; ++j) {
        if (km & (1 << j)) {   // km wave-uniform -> no divergence
            int nb = neigh[row * KNBR + j];
            float dn = dinv[nb];
            float2 v = nxt2[nb * 64 + lane];
            ax = fmaf(dn, v.x, ax);
            ay = fmaf(dn, v.y, ay);
        }
    }
    float2 r = ((const float2*)resid)[row * 64 + lane];
    float vx = fmaxf(di * ax, 0.f) + r.x;
    float vy = fmaxf(di * ay, 0.f) + r.y;

    float mu = wave_sum(vx + vy) * (1.f / 128.f);
    float dx = vx - mu, dy = vy - mu;
    float var = wave_sum(dx * dx + dy * dy) * (1.f / 128.f);
    float rs = rsqrtf(var + EPSF);

    float2 gg = ((const float2*)g)[lane];
    float2 bb = ((const float2*)b)[lane];
    float2 o;
    o.x = dx * rs * gg.x + bb.x;
    o.y = dy * rs * gg.y + bb.y;
    *reinterpret_cast<float2*>(out + (size_t)row * outStride + outOffset + lane * 2) = o;
}

// ---------------------------------------------------------------------------
// SAGE max-pool over first cnt neighbors (no dedupe, self allowed); 0 if cnt==0.
// ---------------------------------------------------------------------------
__global__ __launch_bounds__(256)
void pool_kernel(const float* __restrict__ enc, const int* __restrict__ neigh,
                 const int* __restrict__ cnt, float* __restrict__ out) {
    int row = blockIdx.x * 4 + (threadIdx.x >> 6);
    int lane = threadIdx.x & 63;
    int c = cnt[row];
    float2 acc = make_float2(0.f, 0.f);
    if (c > 0) {   // wave-uniform branch
        acc = make_float2(-1e30f, -1e30f);
        for (int j = 0; j < c; ++j) {
            int nb = neigh[row * KNBR + j];
            float2 v = ((const float2*)enc)[nb * 64 + lane];
            acc.x = fmaxf(acc.x, v.x);
            acc.y = fmaxf(acc.y, v.y);
        }
    }
    ((float2*)out)[row * 64 + lane] = acc;
}

// ---------------------------------------------------------------------------
// SAGE: s_new = LN(nxt + s_prev)
// ---------------------------------------------------------------------------
__global__ __launch_bounds__(256)
void add_ln_kernel(const float* __restrict__ nxt, const float* __restrict__ sprev,
                   const float* __restrict__ g, const float* __restrict__ b,
                   float* __restrict__ out, int outStride, int outOffset) {
    int row = blockIdx.x * 4 + (threadIdx.x >> 6);
    int lane = threadIdx.x & 63;
    float2 a = ((const float2*)nxt)[row * 64 + lane];
    float2 r = ((const float2*)sprev)[row * 64 + lane];
    float vx = a.x + r.x, vy = a.y + r.y;

    float mu = wave_sum(vx + vy) * (1.f / 128.f);
    float dx = vx - mu, dy = vy - mu;
    float var = wave_sum(dx * dx + dy * dy) * (1.f / 128.f);
    float rs = rsqrtf(var + EPSF);

    float2 gg = ((const float2*)g)[lane];
    float2 bb = ((const float2*)b)[lane];
    float2 o;
    o.x = dx * rs * gg.x + bb.x;
    o.y = dy * rs * gg.y + bb.y;
    *reinterpret_cast<float2*>(out + (size_t)row * outStride + outOffset + lane * 2) = o;
}

extern "C" void kernel_launch(void* const* d_in, const int* in_sizes, int n_in,
                              void* d_out, int out_size, void* d_ws, size_t ws_size,
                              hipStream_t stream) {
    (void)in_sizes; (void)n_in; (void)out_size; (void)ws_size;
    const float* x      = (const float*)d_in[0];
    const int*   neigh  = (const int*)d_in[1];
    const int*   cnt    = (const int*)d_in[2];
    const float* gcnW   = (const float*)d_in[3];
    const float* gcnB   = (const float*)d_in[4];
    const float* gcnG   = (const float*)d_in[5];
    const float* gcnBb  = (const float*)d_in[6];
    const float* poolW  = (const float*)d_in[7];
    const float* poolB  = (const float*)d_in[8];
    const float* mW     = (const float*)d_in[9];
    const float* mB     = (const float*)d_in[10];
    const float* sg     = (const float*)d_in[11];
    const float* sb     = (const float*)d_in[12];
    float* out = (float*)d_out;

    char* ws = (char*)d_ws;
    float* dinv = (float*)ws;                       // 8192 f
    int*   kept = (int*)(ws + 32 * 1024);           // 8192 i
    float* bufA = (float*)(ws + 64 * 1024);         // N*D each
    float* bufB = bufA + NND * DD;
    float* bufC = bufB + NND * DD;

    dim3 blk(256);
    dim3 ggrid(NND / 64, DD / 16);   // (128, 8) = 1024 blocks -> 4 blocks/CU
    dim3 rgrid(NND / 4);

    deg_kernel<<<dim3(NND / 256), blk, 0, stream>>>(neigh, cnt, dinv, kept);

    // ---------------- GCN branch ----------------
    gemm_kernel<false><<<ggrid, blk, 0, stream>>>(x, gcnW + 0 * DD * DD,
                                                  gcnB + 0 * DD, bufA);
    prop_ln_kernel<<<rgrid, blk, 0, stream>>>(bufA, bufA, dinv, kept, neigh,
                                              gcnG + 0 * DD, gcnBb + 0 * DD, bufB, DD, 0);
    gemm_kernel<false><<<ggrid, blk, 0, stream>>>(bufB, gcnW + 1 * DD * DD,
                                                  gcnB + 1 * DD, bufA);
    prop_ln_kernel<<<rgrid, blk, 0, stream>>>(bufA, bufB, dinv, kept, neigh,
                                              gcnG + 1 * DD, gcnBb + 1 * DD, bufC, DD, 0);
    gemm_kernel<false><<<ggrid, blk, 0, stream>>>(bufC, gcnW + 2 * DD * DD,
                                                  gcnB + 2 * DD, bufA);
    prop_ln_kernel<<<rgrid, blk, 0, stream>>>(bufA, bufC, dinv, kept, neigh,
                                              gcnG + 2 * DD, gcnBb + 2 * DD, out, 2 * DD, 0);

    // ---------------- SAGE branch ----------------
    gemm_kernel<true><<<ggrid, blk, 0, stream>>>(x, poolW, poolB, bufA);     // ne1
    pool_kernel<<<rgrid, blk, 0, stream>>>(bufA, neigh, cnt, bufB);          // p1
    gemm2_kernel<<<ggrid, blk, 0, stream>>>(x, bufB, mW + 0 * DD * 2 * DD,
                                            mB + 0 * DD, bufC);              // s1
    pool_kernel<<<rgrid, blk, 0, stream>>>(bufC, neigh, cnt, bufA);          // p2
    gemm2_kernel<<<ggrid, blk, 0, stream>>>(bufC, bufA, mW + 1 * DD * 2 * DD,
                                            mB + 1 * DD, bufB);
    add_ln_kernel<<<rgrid, blk, 0, stream>>>(bufB, bufC, sg + 0 * DD, sb + 0 * DD,
                                             bufA, DD, 0);                   // s2
    pool_kernel<<<rgrid, blk, 0, stream>>>(bufA, neigh, cnt, bufB);          // p3
    gemm2_kernel<<<ggrid, blk, 0, stream>>>(bufA, bufB, mW + 2 * DD * 2 * DD,
                                            mB + 2 * DD, bufC);
    add_ln_kernel<<<rgrid, blk, 0, stream>>>(bufC, bufA, sg + 1 * DD, sb + 1 * DD,
                                             out, 2 * DD, DD);
}

// Round 4
// 239.359 us; speedup vs baseline: 1.4807x; 1.1559x over previous
//
#include <hip/hip_runtime.h>

#define NND 8192
#define KNBR 8
#define DD 128
#define EPSF 1e-5f
#define SHSTRIDE 130   // 64x128 tile, +2 pad

// ---------------------------------------------------------------------------
// Degree / dinv: deg[i] = 1 (self) + #distinct valid neighbors != i.
// ---------------------------------------------------------------------------
__global__ __launch_bounds__(256)
void deg_kernel(const int* __restrict__ neigh, const int* __restrict__ cnt,
                float* __restrict__ dinv, int* __restrict__ kept) {
    int i = blockIdx.x * 256 + threadIdx.x;
    if (i >= NND) return;
    int c = cnt[i];
    int nb[KNBR];
#pragma unroll
    for (int j = 0; j < KNBR; ++j) nb[j] = neigh[i * KNBR + j];
    int mask = 0, deg = 1;
#pragma unroll
    for (int j = 0; j < KNBR; ++j) {
        if (j < c) {
            int v = nb[j];
            bool dup = (v == i);
            for (int jj = 0; jj < j; ++jj)
                if (nb[jj] == v) { dup = true; }
            if (!dup) { mask |= (1 << j); deg++; }
        }
    }
    dinv[i] = rsqrtf((float)deg);
    kept[i] = mask;
}

// ---------------------------------------------------------------------------
// GEMM helpers: 64-row x 128-K tile in LDS; wave handles 4 output cols
// (wave-uniform W index -> scalar loads); lane = row.
// ---------------------------------------------------------------------------
__device__ __forceinline__ void stage_tile(float* sh, const float* __restrict__ src,
                                           int tid) {
#pragma unroll
    for (int it = 0; it < 8; ++it) {
        int idx = tid + it * 256;
        int m = idx >> 5;
        int d4 = idx & 31;
        float4 v = *reinterpret_cast<const float4*>(src + m * DD + d4 * 4);
        float* dst = &sh[m * SHSTRIDE + d4 * 4];
        dst[0] = v.x; dst[1] = v.y; dst[2] = v.z; dst[3] = v.w;
    }
}

__device__ __forceinline__ void accum_tile(const float* sh, int lane,
                                           const float* __restrict__ Wbase,
                                           int wStride, int o0, float acc[4]) {
    const float* shrow = &sh[lane * SHSTRIDE];
    for (int d = 0; d < DD; d += 4) {
        float2 h01 = *reinterpret_cast<const float2*>(shrow + d);
        float2 h23 = *reinterpret_cast<const float2*>(shrow + d + 2);
#pragma unroll
        for (int c = 0; c < 4; ++c) {
            const float4 wv =
                *reinterpret_cast<const float4*>(Wbase + (size_t)(o0 + c) * wStride + d);
            acc[c] = fmaf(h01.x, wv.x, acc[c]);
            acc[c] = fmaf(h01.y, wv.y, acc[c]);
            acc[c] = fmaf(h23.x, wv.z, acc[c]);
            acc[c] = fmaf(h23.y, wv.w, acc[c]);
        }
    }
}

// ---------------------------------------------------------------------------
// Mega-GEMM from x: grid (128, 24). Group 0 -> G0 = x@gcnW0^T + gcnB0
//                   group 1 -> E1 = relu(x@poolW^T + poolB)
//                   group 2 -> S1p = x@mW0[:, :D]^T + mB0   (stride 2D)
// ---------------------------------------------------------------------------
__global__ __launch_bounds__(256)
void mega_gemm(const float* __restrict__ x,
               const float* __restrict__ gW0, const float* __restrict__ gB0,
               const float* __restrict__ pW, const float* __restrict__ pB,
               const float* __restrict__ mW0, const float* __restrict__ mB0,
               float* __restrict__ G, float* __restrict__ E, float* __restrict__ S) {
    __shared__ float sh[64 * SHSTRIDE];
    const int tid = threadIdx.x;
    const int rowBase = blockIdx.x * 64;
    stage_tile(sh, x + (size_t)rowBase * DD, tid);
    __syncthreads();

    const int lane = tid & 63;
    const int w = __builtin_amdgcn_readfirstlane(tid >> 6);
    const int grp = blockIdx.y >> 3;
    const int o0 = (blockIdx.y & 7) * 16 + w * 4;

    const float* W; const float* bias; float* dst; int ws; bool relu;
    if (grp == 0)      { W = gW0; bias = gB0; dst = G; ws = DD;     relu = false; }
    else if (grp == 1) { W = pW;  bias = pB;  dst = E; ws = DD;     relu = true;  }
    else               { W = mW0; bias = mB0; dst = S; ws = 2 * DD; relu = false; }

    float acc[4] = {0.f, 0.f, 0.f, 0.f};
    accum_tile(sh, lane, W, ws, o0, acc);

    float4 v;
    v.x = acc[0] + bias[o0 + 0];
    v.y = acc[1] + bias[o0 + 1];
    v.z = acc[2] + bias[o0 + 2];
    v.w = acc[3] + bias[o0 + 3];
    if (relu) {
        v.x = fmaxf(v.x, 0.f); v.y = fmaxf(v.y, 0.f);
        v.z = fmaxf(v.z, 0.f); v.w = fmaxf(v.w, 0.f);
    }
    *reinterpret_cast<float4*>(dst + (size_t)(rowBase + lane) * DD + o0) = v;
}

// ---------------------------------------------------------------------------
// Dual GEMM, step 4: grid (128, 8, 2).
//  z=0: S1 = relu(S1p + P1 @ mW0[:, D:2D]^T)   (S in/out, accumulate)
//  z=1: G1 = H1 @ gcnW1^T + gcnB1
// ---------------------------------------------------------------------------
__global__ __launch_bounds__(256)
void gemm_step4(const float* __restrict__ P, const float* __restrict__ mW0,
                const float* __restrict__ H1, const float* __restrict__ gW1,
                const float* __restrict__ gB1,
                float* __restrict__ S, float* __restrict__ G) {
    __shared__ float sh[64 * SHSTRIDE];
    const int tid = threadIdx.x;
    const int rowBase = blockIdx.x * 64;
    const int lane = tid & 63;
    const int w = __builtin_amdgcn_readfirstlane(tid >> 6);
    const int o0 = blockIdx.y * 16 + w * 4;
    float acc[4] = {0.f, 0.f, 0.f, 0.f};

    if (blockIdx.z == 0) {
        stage_tile(sh, P + (size_t)rowBase * DD, tid);
        __syncthreads();
        accum_tile(sh, lane, mW0 + DD, 2 * DD, o0, acc);
        float* orow = S + (size_t)(rowBase + lane) * DD + o0;
        float4 prev = *reinterpret_cast<const float4*>(orow);
        float4 v;
        v.x = fmaxf(prev.x + acc[0], 0.f);
        v.y = fmaxf(prev.y + acc[1], 0.f);
        v.z = fmaxf(prev.z + acc[2], 0.f);
        v.w = fmaxf(prev.w + acc[3], 0.f);
        *reinterpret_cast<float4*>(orow) = v;
    } else {
        stage_tile(sh, H1 + (size_t)rowBase * DD, tid);
        __syncthreads();
        accum_tile(sh, lane, gW1, DD, o0, acc);
        float4 v;
        v.x = acc[0] + gB1[o0 + 0];
        v.y = acc[1] + gB1[o0 + 1];
        v.z = acc[2] + gB1[o0 + 2];
        v.w = acc[3] + gB1[o0 + 3];
        *reinterpret_cast<float4*>(G + (size_t)(rowBase + lane) * DD + o0) = v;
    }
}

// ---------------------------------------------------------------------------
// Dual GEMM, step 6: grid (128, 8, 2).
//  z=0: T = relu([S1 | P2] @ mW1^T + mB1)   (two-phase concat)
//  z=1: G2 = H2 @ gcnW2^T + gcnB2
// ---------------------------------------------------------------------------
__global__ __launch_bounds__(256)
void gemm_step6(const float* __restrict__ S1, const float* __restrict__ P2,
                const float* __restrict__ mW1, const float* __restrict__ mB1,
                const float* __restrict__ H2, const float* __restrict__ gW2,
                const float* __restrict__ gB2,
                float* __restrict__ T, float* __restrict__ G) {
    __shared__ float sh[64 * SHSTRIDE];
    const int tid = threadIdx.x;
    const int rowBase = blockIdx.x * 64;
    const int lane = tid & 63;
    const int w = __builtin_amdgcn_readfirstlane(tid >> 6);
    const int o0 = blockIdx.y * 16 + w * 4;
    float acc[4] = {0.f, 0.f, 0.f, 0.f};

    if (blockIdx.z == 0) {
        stage_tile(sh, S1 + (size_t)rowBase * DD, tid);
        __syncthreads();
        accum_tile(sh, lane, mW1, 2 * DD, o0, acc);
        __syncthreads();
        stage_tile(sh, P2 + (size_t)rowBase * DD, tid);
        __syncthreads();
        accum_tile(sh, lane, mW1 + DD, 2 * DD, o0, acc);
        float4 v;
        v.x = fmaxf(acc[0] + mB1[o0 + 0], 0.f);
        v.y = fmaxf(acc[1] + mB1[o0 + 1], 0.f);
        v.z = fmaxf(acc[2] + mB1[o0 + 2], 0.f);
        v.w = fmaxf(acc[3] + mB1[o0 + 3], 0.f);
        *reinterpret_cast<float4*>(T + (size_t)(rowBase + lane) * DD + o0) = v;
    } else {
        stage_tile(sh, H2 + (size_t)rowBase * DD, tid);
        __syncthreads();
        accum_tile(sh, lane, gW2, DD, o0, acc);
        float4 v;
        v.x = acc[0] + gB2[o0 + 0];
        v.y = acc[1] + gB2[o0 + 1];
        v.z = acc[2] + gB2[o0 + 2];
        v.w = acc[3] + gB2[o0 + 3];
        *reinterpret_cast<float4*>(G + (size_t)(rowBase + lane) * DD + o0) = v;
    }
}

// Plain concat-GEMM (step 9): T = relu([A1|A2] @ W^T + bias)
__global__ __launch_bounds__(256)
void gemm2_kernel(const float* __restrict__ A1, const float* __restrict__ A2,
                  const float* __restrict__ W, const float* __restrict__ bias,
                  float* __restrict__ out) {
    __shared__ float sh[64 * SHSTRIDE];
    const int tid = threadIdx.x;
    const int rowBase = blockIdx.x * 64;
    const int lane = tid & 63;
    const int w = __builtin_amdgcn_readfirstlane(tid >> 6);
    const int o0 = blockIdx.y * 16 + w * 4;
    float acc[4] = {0.f, 0.f, 0.f, 0.f};

    stage_tile(sh, A1 + (size_t)rowBase * DD, tid);
    __syncthreads();
    accum_tile(sh, lane, W, 2 * DD, o0, acc);
    __syncthreads();
    stage_tile(sh, A2 + (size_t)rowBase * DD, tid);
    __syncthreads();
    accum_tile(sh, lane, W + DD, 2 * DD, o0, acc);

    float4 v;
    v.x = fmaxf(acc[0] + bias[o0 + 0], 0.f);
    v.y = fmaxf(acc[1] + bias[o0 + 1], 0.f);
    v.z = fmaxf(acc[2] + bias[o0 + 2], 0.f);
    v.w = fmaxf(acc[3] + bias[o0 + 3], 0.f);
    *reinterpret_cast<float4*>(out + (size_t)(rowBase + lane) * DD + o0) = v;
}

// ---------------------------------------------------------------------------
// Row-wise device helpers (one wave per row, float2 per lane).
// ---------------------------------------------------------------------------
__device__ __forceinline__ float wave_sum(float s) {
#pragma unroll
    for (int m = 1; m < 64; m <<= 1) s += __shfl_xor(s, m, 64);
    return s;
}

__device__ __forceinline__ void prop_ln_row(int row, int lane,
        const float* __restrict__ nxt, const float* __restrict__ resid,
        const float* __restrict__ dinv, const int* __restrict__ kept,
        const int* __restrict__ neigh,
        const float* __restrict__ g, const float* __restrict__ b,
        float* __restrict__ out, int oStride, int oOff) {
    const float2* nxt2 = (const float2*)nxt;
    float di = dinv[row];
    int km = kept[row];
    float2 self = nxt2[row * 64 + lane];
    float ax = di * self.x, ay = di * self.y;
#pragma unroll
    for (int j = 0; j < KNBR; ++j) {
        if (km & (1 << j)) {
            int nb = neigh[row * KNBR + j];
            float dn = dinv[nb];
            float2 v = nxt2[nb * 64 + lane];
            ax = fmaf(dn, v.x, ax);
            ay = fmaf(dn, v.y, ay);
        }
    }
    float2 r = ((const float2*)resid)[row * 64 + lane];
    float vx = fmaxf(di * ax, 0.f) + r.x;
    float vy = fmaxf(di * ay, 0.f) + r.y;
    float mu = wave_sum(vx + vy) * (1.f / 128.f);
    float dx = vx - mu, dy = vy - mu;
    float var = wave_sum(dx * dx + dy * dy) * (1.f / 128.f);
    float rs = rsqrtf(var + EPSF);
    float2 gg = ((const float2*)g)[lane];
    float2 bb = ((const float2*)b)[lane];
    float2 o;
    o.x = dx * rs * gg.x + bb.x;
    o.y = dy * rs * gg.y + bb.y;
    *reinterpret_cast<float2*>(out + (size_t)row * oStride + oOff + lane * 2) = o;
}

__device__ __forceinline__ void pool_row(int row, int lane,
        const float* __restrict__ enc, const int* __restrict__ neigh,
        const int* __restrict__ cnt, float* __restrict__ P) {
    int c = cnt[row];
    float2 acc = make_float2(0.f, 0.f);
    if (c > 0) {
        acc = make_float2(-1e30f, -1e30f);
        for (int j = 0; j < c; ++j) {
            int nb = neigh[row * KNBR + j];
            float2 v = ((const float2*)enc)[nb * 64 + lane];
            acc.x = fmaxf(acc.x, v.x);
            acc.y = fmaxf(acc.y, v.y);
        }
    }
    ((float2*)P)[row * 64 + lane] = acc;
}

__device__ __forceinline__ void add_ln_row(int row, int lane,
        const float* __restrict__ nxt, const float* __restrict__ sprev,
        const float* __restrict__ g, const float* __restrict__ b,
        float* __restrict__ out, int oStride, int oOff) {
    float2 a = ((const float2*)nxt)[row * 64 + lane];
    float2 r = ((const float2*)sprev)[row * 64 + lane];
    float vx = a.x + r.x, vy = a.y + r.y;
    float mu = wave_sum(vx + vy) * (1.f / 128.f);
    float dx = vx - mu, dy = vy - mu;
    float var = wave_sum(dx * dx + dy * dy) * (1.f / 128.f);
    float rs = rsqrtf(var + EPSF);
    float2 gg = ((const float2*)g)[lane];
    float2 bb = ((const float2*)b)[lane];
    float2 o;
    o.x = dx * rs * gg.x + bb.x;
    o.y = dy * rs * gg.y + bb.y;
    *reinterpret_cast<float2*>(out + (size_t)row * oStride + oOff + lane * 2) = o;
}

// Fused row-wise: GCN prop+LN AND SAGE pool in one dispatch.
__global__ __launch_bounds__(256)
void prop_pool_kernel(const float* __restrict__ nxt, const float* __restrict__ resid,
                      const float* __restrict__ dinv, const int* __restrict__ kept,
                      const int* __restrict__ neigh, const int* __restrict__ cnt,
                      const float* __restrict__ g, const float* __restrict__ b,
                      float* __restrict__ outH, int oStride, int oOff,
                      const float* __restrict__ enc, float* __restrict__ P) {
    int row = blockIdx.x * 4 + (threadIdx.x >> 6);
    int lane = threadIdx.x & 63;
    prop_ln_row(row, lane, nxt, resid, dinv, kept, neigh, g, b, outH, oStride, oOff);
    pool_row(row, lane, enc, neigh, cnt, P);
}

// Fused row-wise: GCN prop+LN AND SAGE add+LN in one dispatch.
__global__ __launch_bounds__(256)
void prop_addln_kernel(const float* __restrict__ nxt, const float* __restrict__ resid,
                       const float* __restrict__ dinv, const int* __restrict__ kept,
                       const int* __restrict__ neigh,
                       const float* __restrict__ g, const float* __restrict__ b,
                       float* __restrict__ outH, int oStride, int oOff,
                       const float* __restrict__ snxt, const float* __restrict__ sprev,
                       const float* __restrict__ sg, const float* __restrict__ sb,
                       float* __restrict__ outS) {
    int row = blockIdx.x * 4 + (threadIdx.x >> 6);
    int lane = threadIdx.x & 63;
    prop_ln_row(row, lane, nxt, resid, dinv, kept, neigh, g, b, outH, oStride, oOff);
    add_ln_row(row, lane, snxt, sprev, sg, sb, outS, DD, 0);
}

__global__ __launch_bounds__(256)
void pool_kernel(const float* __restrict__ enc, const int* __restrict__ neigh,
                 const int* __restrict__ cnt, float* __restrict__ out) {
    int row = blockIdx.x * 4 + (threadIdx.x >> 6);
    int lane = threadIdx.x & 63;
    pool_row(row, lane, enc, neigh, cnt, out);
}

__global__ __launch_bounds__(256)
void add_ln_kernel(const float* __restrict__ nxt, const float* __restrict__ sprev,
                   const float* __restrict__ g, const float* __restrict__ b,
                   float* __restrict__ out, int oStride, int oOff) {
    int row = blockIdx.x * 4 + (threadIdx.x >> 6);
    int lane = threadIdx.x & 63;
    add_ln_row(row, lane, nxt, sprev, g, b, out, oStride, oOff);
}

extern "C" void kernel_launch(void* const* d_in, const int* in_sizes, int n_in,
                              void* d_out, int out_size, void* d_ws, size_t ws_size,
                              hipStream_t stream) {
    (void)in_sizes; (void)n_in; (void)out_size; (void)ws_size;
    const float* x      = (const float*)d_in[0];
    const int*   neigh  = (const int*)d_in[1];
    const int*   cnt    = (const int*)d_in[2];
    const float* gcnW   = (const float*)d_in[3];
    const float* gcnB   = (const float*)d_in[4];
    const float* gcnG   = (const float*)d_in[5];
    const float* gcnBb  = (const float*)d_in[6];
    const float* poolW  = (const float*)d_in[7];
    const float* poolB  = (const float*)d_in[8];
    const float* mW     = (const float*)d_in[9];
    const float* mB     = (const float*)d_in[10];
    const float* sg     = (const float*)d_in[11];
    const float* sb     = (const float*)d_in[12];
    float* out = (float*)d_out;

    char* ws = (char*)d_ws;
    float* dinv = (float*)ws;                   // 8192 f
    int*   kept = (int*)(ws + 32 * 1024);       // 8192 i
    float* G  = (float*)(ws + 64 * 1024);       // 4 MB each
    float* H1 = G  + NND * DD;
    float* H2 = H1 + NND * DD;
    float* E  = H2 + NND * DD;
    float* P  = E  + NND * DD;
    float* S1 = P  + NND * DD;
    float* S2 = S1 + NND * DD;
    float* T  = S2 + NND * DD;

    dim3 blk(256);
    dim3 mgrid(NND / 64, 24);        // mega-GEMM: 3 x 128 cols
    dim3 dgrid(NND / 64, 8, 2);      // dual GEMMs
    dim3 ggrid(NND / 64, 8);         // single concat GEMM
    dim3 rgrid(NND / 4);             // row-wise

    // 1. degree / dedupe
    deg_kernel<<<dim3(NND / 256), blk, 0, stream>>>(neigh, cnt, dinv, kept);
    // 2. [G0 | E1 | S1p] from x
    mega_gemm<<<mgrid, blk, 0, stream>>>(x, gcnW, gcnB, poolW, poolB,
                                         mW, mB, G, E, S1);
    // 3. H1 = propLN(G0, resid=G0); P1 = pool(E1)
    prop_pool_kernel<<<rgrid, blk, 0, stream>>>(G, G, dinv, kept, neigh, cnt,
                                                gcnG, gcnBb, H1, DD, 0, E, P);
    // 4. S1 = relu(S1p + P1@mW0R^T); G1 = H1@gcnW1^T + b1
    gemm_step4<<<dgrid, blk, 0, stream>>>(P, mW, H1, gcnW + DD * DD,
                                          gcnB + DD, S1, G);
    // 5. H2 = propLN(G1, resid=H1); P2 = pool(S1)
    prop_pool_kernel<<<rgrid, blk, 0, stream>>>(G, H1, dinv, kept, neigh, cnt,
                                                gcnG + DD, gcnBb + DD, H2, DD, 0,
                                                S1, P);
    // 6. T = relu([S1|P2]@mW1^T + mB1); G2 = H2@gcnW2^T + b2
    gemm_step6<<<dgrid, blk, 0, stream>>>(S1, P, mW + DD * 2 * DD, mB + DD,
                                          H2, gcnW + 2 * DD * DD, gcnB + 2 * DD,
                                          T, G);
    // 7. outL = propLN(G2, resid=H2); S2 = LN(T + S1)
    prop_addln_kernel<<<rgrid, blk, 0, stream>>>(G, H2, dinv, kept, neigh,
                                                 gcnG + 2 * DD, gcnBb + 2 * DD,
                                                 out, 2 * DD, 0,
                                                 T, S1, sg, sb, S2);
    // 8. P3 = pool(S2)
    pool_kernel<<<rgrid, blk, 0, stream>>>(S2, neigh, cnt, P);
    // 9. T = relu([S2|P3]@mW2^T + mB2)
    gemm2_kernel<<<ggrid, blk, 0, stream>>>(S2, P, mW + 2 * DD * 2 * DD,
                                            mB + 2 * DD, T);
    // 10. outR = LN(T + S2)
    add_ln_kernel<<<rgrid, blk, 0, stream>>>(T, S2, sg + DD, sb + DD,
                                             out, 2 * DD, DD);
}

// Round 5
// 183.431 us; speedup vs baseline: 1.9322x; 1.3049x over previous
//
#include <hip/hip_runtime.h>

#define NND 8192
#define KNBR 8
#define DD 128
#define EPSF 1e-5f
#define BSTR 264   // LDS B-tile row stride in shorts (132 dwords = 4 mod 32 banks -> 2-way, free)

// bf16 weight buffer layout (offsets in shorts)
#define WOFF_GCN0 0
#define WOFF_GCN1 16384
#define WOFF_GCN2 32768
#define WOFF_POOL 49152
#define WOFF_M0   65536
#define WOFF_M1   98304
#define WOFF_M2   131072
#define WTOTAL    163840

typedef __attribute__((ext_vector_type(8))) short bf16x8;
typedef __attribute__((ext_vector_type(4))) float f32x4;

__device__ __forceinline__ unsigned short f2bf(float f) {
    unsigned u = __float_as_uint(f);
    u += 0x7FFF + ((u >> 16) & 1);   // round-to-nearest-even
    return (unsigned short)(u >> 16);
}

// ---------------------------------------------------------------------------
// Fused: degree/dedupe (blocks 0..31) + weight fp32->bf16 convert (blocks 32..671)
// ---------------------------------------------------------------------------
__global__ __launch_bounds__(256)
void deg_cvt_kernel(const int* __restrict__ neigh, const int* __restrict__ cnt,
                    const float* __restrict__ gcnW, const float* __restrict__ poolW,
                    const float* __restrict__ mW,
                    float* __restrict__ dinv, int* __restrict__ kept,
                    unsigned short* __restrict__ wbuf) {
    int bx = blockIdx.x;
    if (bx < 32) {
        int i = bx * 256 + threadIdx.x;
        int c = cnt[i];
        int nb[KNBR];
#pragma unroll
        for (int j = 0; j < KNBR; ++j) nb[j] = neigh[i * KNBR + j];
        int mask = 0, deg = 1;
#pragma unroll
        for (int j = 0; j < KNBR; ++j) {
            if (j < c) {
                int v = nb[j];
                bool dup = (v == i);
                for (int jj = 0; jj < j; ++jj)
                    if (nb[jj] == v) { dup = true; }
                if (!dup) { mask |= (1 << j); deg++; }
            }
        }
        dinv[i] = rsqrtf((float)deg);
        kept[i] = mask;
    } else {
        int i = (bx - 32) * 256 + threadIdx.x;   // 0..163839
        float v;
        if (i < 49152) v = gcnW[i];
        else if (i < 65536) v = poolW[i - 49152];
        else v = mW[i - 65536];
        wbuf[i] = f2bf(v);
    }
}

// ---------------------------------------------------------------------------
// MFMA GEMM building blocks. Per wave: one 16x16 output tile, K=128 (4 mfma).
// A: fp32 global row-major [m][K], converted to bf16 in-reg.
// B: bf16 LDS tile, 16 rows (= output cols) x K, row stride BSTR shorts.
// Layouts (guide §3, m89/m91-verified): A[m=lane&15][k=quad*8+j],
// B[k][n=lane&15] from W[n][k] 16B slices, C/D col=lane&15 row=quad*4+reg.
// ---------------------------------------------------------------------------
__device__ __forceinline__ void stage_b128(unsigned short* sh,
        const unsigned short* __restrict__ W, int wstride, int tid) {
    int r = tid >> 4;            // 16 rows
    int c = (tid & 15) * 8;      // 128 shorts/row
    *(bf16x8*)(sh + r * BSTR + c) = *(const bf16x8*)(W + (size_t)r * wstride + c);
}

__device__ __forceinline__ void stage_b256(unsigned short* sh,
        const unsigned short* __restrict__ W, int wstride, int tid) {
    int r = tid >> 4;
    int c = (tid & 15) * 16;     // 256 shorts/row
    *(bf16x8*)(sh + r * BSTR + c) = *(const bf16x8*)(W + (size_t)r * wstride + c);
    *(bf16x8*)(sh + r * BSTR + c + 8) = *(const bf16x8*)(W + (size_t)r * wstride + c + 8);
}

__device__ __forceinline__ bf16x8 afrag(const float* __restrict__ Arow, int k0) {
    float4 lo = *(const float4*)(Arow + k0);
    float4 hi = *(const float4*)(Arow + k0 + 4);
    bf16x8 r;
    r[0] = f2bf(lo.x); r[1] = f2bf(lo.y); r[2] = f2bf(lo.z); r[3] = f2bf(lo.w);
    r[4] = f2bf(hi.x); r[5] = f2bf(hi.y); r[6] = f2bf(hi.z); r[7] = f2bf(hi.w);
    return r;
}

__device__ __forceinline__ f32x4 mma128(const float* __restrict__ A, int strideA,
                                        int rowBase, const unsigned short* shB,
                                        int lane, f32x4 acc) {
    int idx = lane & 15, q = lane >> 4;
    const float* Arow = A + (size_t)(rowBase + idx) * strideA;
#pragma unroll
    for (int s = 0; s < 4; ++s) {
        bf16x8 af = afrag(Arow, s * 32 + q * 8);
        bf16x8 bf = *(const bf16x8*)(shB + idx * BSTR + s * 32 + q * 8);
        acc = __builtin_amdgcn_mfma_f32_16x16x32_bf16(af, bf, acc, 0, 0, 0);
    }
    return acc;
}

__device__ __forceinline__ void store_tile(float* __restrict__ out, int ostride,
        int oOff, int rowBase, int colBase, int lane, f32x4 c,
        const float* __restrict__ bias, bool relu) {
    int idx = lane & 15, q = lane >> 4;
    float b = bias[colBase + idx];
#pragma unroll
    for (int r = 0; r < 4; ++r) {
        float v = c[r] + b;
        if (relu) v = fmaxf(v, 0.f);
        out[(size_t)(rowBase + q * 4 + r) * ostride + oOff + colBase + idx] = v;
    }
}

// ---------------------------------------------------------------------------
// Mega-GEMM from x: grid (128, 24). grp 0 -> G0 = x@gcnW0^T + gcnB0
//   grp 1 -> E1 = relu(x@poolW^T + poolB); grp 2 -> S1p = x@mW0L^T + mB0
// ---------------------------------------------------------------------------
__global__ __launch_bounds__(256)
void mega_gemm(const float* __restrict__ x, const unsigned short* __restrict__ wbuf,
               const float* __restrict__ gB0, const float* __restrict__ pB,
               const float* __restrict__ mB0,
               float* __restrict__ G, float* __restrict__ E, float* __restrict__ S) {
    __shared__ unsigned short shB[16 * BSTR];
    const int tid = threadIdx.x;
    const int grp = blockIdx.y >> 3;
    const int nt = blockIdx.y & 7;
    const int colBase = nt * 16;

    const unsigned short* W; const float* bias; float* dst; int wstr; bool relu = false;
    if (grp == 0)      { W = wbuf + WOFF_GCN0; bias = gB0; dst = G; wstr = 128; }
    else if (grp == 1) { W = wbuf + WOFF_POOL; bias = pB;  dst = E; wstr = 128; relu = true; }
    else               { W = wbuf + WOFF_M0;   bias = mB0; dst = S; wstr = 256; }

    stage_b128(shB, W + (size_t)colBase * wstr, wstr, tid);
    __syncthreads();

    const int lane = tid & 63;
    const int w = tid >> 6;
    const int rowBase = (blockIdx.x * 4 + w) * 16;
    f32x4 acc = {0.f, 0.f, 0.f, 0.f};
    acc = mma128(x, DD, rowBase, shB, lane, acc);
    store_tile(dst, DD, 0, rowBase, colBase, lane, acc, bias, relu);
}

// ---------------------------------------------------------------------------
// step4: grid (128, 8, 2).
//  z=0: S1 = relu(S1p + P1 @ mW0R^T)   (in/out accumulate)
//  z=1: G1 = H1 @ gcnW1^T + gcnB1
// ---------------------------------------------------------------------------
__global__ __launch_bounds__(256)
void gemm_step4(const float* __restrict__ P, const float* __restrict__ H1,
                const unsigned short* __restrict__ wbuf, const float* __restrict__ gB1,
                float* __restrict__ S, float* __restrict__ G) {
    __shared__ unsigned short shB[16 * BSTR];
    const int tid = threadIdx.x;
    const int colBase = blockIdx.y * 16;
    const int lane = tid & 63;
    const int w = tid >> 6;
    const int rowBase = (blockIdx.x * 4 + w) * 16;
    f32x4 acc = {0.f, 0.f, 0.f, 0.f};

    if (blockIdx.z == 0) {
        stage_b128(shB, wbuf + WOFF_M0 + 128 + (size_t)colBase * 256, 256, tid);
        __syncthreads();
        acc = mma128(P, DD, rowBase, shB, lane, acc);
        int idx = lane & 15, q = lane >> 4;
#pragma unroll
        for (int r = 0; r < 4; ++r) {
            size_t o = (size_t)(rowBase + q * 4 + r) * DD + colBase + idx;
            S[o] = fmaxf(S[o] + acc[r], 0.f);
        }
    } else {
        stage_b128(shB, wbuf + WOFF_GCN1 + (size_t)colBase * 128, 128, tid);
        __syncthreads();
        acc = mma128(H1, DD, rowBase, shB, lane, acc);
        store_tile(G, DD, 0, rowBase, colBase, lane, acc, gB1, false);
    }
}

// ---------------------------------------------------------------------------
// step6: grid (128, 8, 2).
//  z=0: T = relu([S1 | P2] @ mW1^T + mB1)   (K=256 concat)
//  z=1: G2 = H2 @ gcnW2^T + gcnB2
// ---------------------------------------------------------------------------
__global__ __launch_bounds__(256)
void gemm_step6(const float* __restrict__ S1, const float* __restrict__ P2,
                const float* __restrict__ H2, const unsigned short* __restrict__ wbuf,
                const float* __restrict__ mB1, const float* __restrict__ gB2,
                float* __restrict__ T, float* __restrict__ G) {
    __shared__ unsigned short shB[16 * BSTR];
    const int tid = threadIdx.x;
    const int colBase = blockIdx.y * 16;
    const int lane = tid & 63;
    const int w = tid >> 6;
    const int rowBase = (blockIdx.x * 4 + w) * 16;
    f32x4 acc = {0.f, 0.f, 0.f, 0.f};

    if (blockIdx.z == 0) {
        stage_b256(shB, wbuf + WOFF_M1 + (size_t)colBase * 256, 256, tid);
        __syncthreads();
        acc = mma128(S1, DD, rowBase, shB, lane, acc);
        acc = mma128(P2, DD, rowBase, shB + 128, lane, acc);
        store_tile(T, DD, 0, rowBase, colBase, lane, acc, mB1, true);
    } else {
        stage_b128(shB, wbuf + WOFF_GCN2 + (size_t)colBase * 128, 128, tid);
        __syncthreads();
        acc = mma128(H2, DD, rowBase, shB, lane, acc);
        store_tile(G, DD, 0, rowBase, colBase, lane, acc, gB2, false);
    }
}

// Final concat GEMM: T = relu([S2 | P3] @ mW2^T + mB2). grid (128, 8)
__global__ __launch_bounds__(256)
void gemm2_mfma(const float* __restrict__ A1, const float* __restrict__ A2,
                const unsigned short* __restrict__ wbuf, const float* __restrict__ bias,
                float* __restrict__ T) {
    __shared__ unsigned short shB[16 * BSTR];
    const int tid = threadIdx.x;
    const int colBase = blockIdx.y * 16;
    const int lane = tid & 63;
    const int w = tid >> 6;
    const int rowBase = (blockIdx.x * 4 + w) * 16;

    stage_b256(shB, wbuf + WOFF_M2 + (size_t)colBase * 256, 256, tid);
    __syncthreads();
    f32x4 acc = {0.f, 0.f, 0.f, 0.f};
    acc = mma128(A1, DD, rowBase, shB, lane, acc);
    acc = mma128(A2, DD, rowBase, shB + 128, lane, acc);
    store_tile(T, DD, 0, rowBase, colBase, lane, acc, bias, true);
}

// ---------------------------------------------------------------------------
// Row-wise (fp32, one wave per row, float2 per lane) — unchanged from R4.
// ---------------------------------------------------------------------------
__device__ __forceinline__ float wave_sum(float s) {
#pragma unroll
    for (int m = 1; m < 64; m <<= 1) s += __shfl_xor(s, m, 64);
    return s;
}

__device__ __forceinline__ void prop_ln_row(int row, int lane,
        const float* __restrict__ nxt, const float* __restrict__ resid,
        const float* __restrict__ dinv, const int* __restrict__ kept,
        const int* __restrict__ neigh,
        const float* __restrict__ g, const float* __restrict__ b,
        float* __restrict__ out, int oStride, int oOff) {
    const float2* nxt2 = (const float2*)nxt;
    float di = dinv[row];
    int km = kept[row];
    float2 self = nxt2[row * 64 + lane];
    float ax = di * self.x, ay = di * self.y;
#pragma unroll
    for (int j = 0; j < KNBR; ++j) {
        if (km & (1 << j)) {
            int nb = neigh[row * KNBR + j];
            float dn = dinv[nb];
            float2 v = nxt2[nb * 64 + lane];
            ax = fmaf(dn, v.x, ax);
            ay = fmaf(dn, v.y, ay);
        }
    }
    float2 r = ((const float2*)resid)[row * 64 + lane];
    float vx = fmaxf(di * ax, 0.f) + r.x;
    float vy = fmaxf(di * ay, 0.f) + r.y;
    float mu = wave_sum(vx + vy) * (1.f / 128.f);
    float dx = vx - mu, dy = vy - mu;
    float var = wave_sum(dx * dx + dy * dy) * (1.f / 128.f);
    float rs = rsqrtf(var + EPSF);
    float2 gg = ((const float2*)g)[lane];
    float2 bb = ((const float2*)b)[lane];
    float2 o;
    o.x = dx * rs * gg.x + bb.x;
    o.y = dy * rs * gg.y + bb.y;
    *reinterpret_cast<float2*>(out + (size_t)row * oStride + oOff + lane * 2) = o;
}

__device__ __forceinline__ void pool_row(int row, int lane,
        const float* __restrict__ enc, const int* __restrict__ neigh,
        const int* __restrict__ cnt, float* __restrict__ P) {
    int c = cnt[row];
    float2 acc = make_float2(0.f, 0.f);
    if (c > 0) {
        acc = make_float2(-1e30f, -1e30f);
        for (int j = 0; j < c; ++j) {
            int nb = neigh[row * KNBR + j];
            float2 v = ((const float2*)enc)[nb * 64 + lane];
            acc.x = fmaxf(acc.x, v.x);
            acc.y = fmaxf(acc.y, v.y);
        }
    }
    ((float2*)P)[row * 64 + lane] = acc;
}

__device__ __forceinline__ void add_ln_row(int row, int lane,
        const float* __restrict__ nxt, const float* __restrict__ sprev,
        const float* __restrict__ g, const float* __restrict__ b,
        float* __restrict__ out, int oStride, int oOff) {
    float2 a = ((const float2*)nxt)[row * 64 + lane];
    float2 r = ((const float2*)sprev)[row * 64 + lane];
    float vx = a.x + r.x, vy = a.y + r.y;
    float mu = wave_sum(vx + vy) * (1.f / 128.f);
    float dx = vx - mu, dy = vy - mu;
    float var = wave_sum(dx * dx + dy * dy) * (1.f / 128.f);
    float rs = rsqrtf(var + EPSF);
    float2 gg = ((const float2*)g)[lane];
    float2 bb = ((const float2*)b)[lane];
    float2 o;
    o.x = dx * rs * gg.x + bb.x;
    o.y = dy * rs * gg.y + bb.y;
    *reinterpret_cast<float2*>(out + (size_t)row * oStride + oOff + lane * 2) = o;
}

__global__ __launch_bounds__(256)
void prop_pool_kernel(const float* __restrict__ nxt, const float* __restrict__ resid,
                      const float* __restrict__ dinv, const int* __restrict__ kept,
                      const int* __restrict__ neigh, const int* __restrict__ cnt,
                      const float* __restrict__ g, const float* __restrict__ b,
                      float* __restrict__ outH, int oStride, int oOff,
                      const float* __restrict__ enc, float* __restrict__ P) {
    int row = blockIdx.x * 4 + (threadIdx.x >> 6);
    int lane = threadIdx.x & 63;
    prop_ln_row(row, lane, nxt, resid, dinv, kept, neigh, g, b, outH, oStride, oOff);
    pool_row(row, lane, enc, neigh, cnt, P);
}

__global__ __launch_bounds__(256)
void prop_addln_kernel(const float* __restrict__ nxt, const float* __restrict__ resid,
                       const float* __restrict__ dinv, const int* __restrict__ kept,
                       const int* __restrict__ neigh,
                       const float* __restrict__ g, const float* __restrict__ b,
                       float* __restrict__ outH, int oStride, int oOff,
                       const float* __restrict__ snxt, const float* __restrict__ sprev,
                       const float* __restrict__ sg, const float* __restrict__ sb,
                       float* __restrict__ outS) {
    int row = blockIdx.x * 4 + (threadIdx.x >> 6);
    int lane = threadIdx.x & 63;
    prop_ln_row(row, lane, nxt, resid, dinv, kept, neigh, g, b, outH, oStride, oOff);
    add_ln_row(row, lane, snxt, sprev, sg, sb, outS, DD, 0);
}

__global__ __launch_bounds__(256)
void pool_kernel(const float* __restrict__ enc, const int* __restrict__ neigh,
                 const int* __restrict__ cnt, float* __restrict__ out) {
    int row = blockIdx.x * 4 + (threadIdx.x >> 6);
    int lane = threadIdx.x & 63;
    pool_row(row, lane, enc, neigh, cnt, out);
}

__global__ __launch_bounds__(256)
void add_ln_kernel(const float* __restrict__ nxt, const float* __restrict__ sprev,
                   const float* __restrict__ g, const float* __restrict__ b,
                   float* __restrict__ out, int oStride, int oOff) {
    int row = blockIdx.x * 4 + (threadIdx.x >> 6);
    int lane = threadIdx.x & 63;
    add_ln_row(row, lane, nxt, sprev, g, b, out, oStride, oOff);
}

extern "C" void kernel_launch(void* const* d_in, const int* in_sizes, int n_in,
                              void* d_out, int out_size, void* d_ws, size_t ws_size,
                              hipStream_t stream) {
    (void)in_sizes; (void)n_in; (void)out_size; (void)ws_size;
    const float* x      = (const float*)d_in[0];
    const int*   neigh  = (const int*)d_in[1];
    const int*   cnt    = (const int*)d_in[2];
    const float* gcnW   = (const float*)d_in[3];
    const float* gcnB   = (const float*)d_in[4];
    const float* gcnG   = (const float*)d_in[5];
    const float* gcnBb  = (const float*)d_in[6];
    const float* poolW  = (const float*)d_in[7];
    const float* poolB  = (const float*)d_in[8];
    const float* mW     = (const float*)d_in[9];
    const float* mB     = (const float*)d_in[10];
    const float* sg     = (const float*)d_in[11];
    const float* sb     = (const float*)d_in[12];
    float* out = (float*)d_out;

    char* ws = (char*)d_ws;
    float* dinv = (float*)ws;                          // 32 KB
    int*   kept = (int*)(ws + 32 * 1024);              // 32 KB
    unsigned short* wbuf = (unsigned short*)(ws + 64 * 1024);   // 320 KB bf16 weights
    float* G  = (float*)(ws + 448 * 1024);             // 4 MB each
    float* H1 = G  + NND * DD;
    float* H2 = H1 + NND * DD;
    float* E  = H2 + NND * DD;
    float* P  = E  + NND * DD;
    float* S1 = P  + NND * DD;
    float* S2 = S1 + NND * DD;
    float* T  = S2 + NND * DD;

    dim3 blk(256);
    dim3 mgrid(NND / 64, 24);
    dim3 dgrid(NND / 64, 8, 2);
    dim3 ggrid(NND / 64, 8);
    dim3 rgrid(NND / 4);

    // 1. degree/dedupe + weight bf16 convert
    deg_cvt_kernel<<<dim3(672), blk, 0, stream>>>(neigh, cnt, gcnW, poolW, mW,
                                                  dinv, kept, wbuf);
    // 2. [G0 | E1 | S1p] from x
    mega_gemm<<<mgrid, blk, 0, stream>>>(x, wbuf, gcnB, poolB, mB, G, E, S1);
    // 3. H1 = propLN(G0, resid=G0); P1 = pool(E1)
    prop_pool_kernel<<<rgrid, blk, 0, stream>>>(G, G, dinv, kept, neigh, cnt,
                                                gcnG, gcnBb, H1, DD, 0, E, P);
    // 4. S1 = relu(S1p + P1@mW0R^T); G1 = H1@gcnW1^T + b1
    gemm_step4<<<dgrid, blk, 0, stream>>>(P, H1, wbuf, gcnB + DD, S1, G);
    // 5. H2 = propLN(G1, resid=H1); P2 = pool(S1)
    prop_pool_kernel<<<rgrid, blk, 0, stream>>>(G, H1, dinv, kept, neigh, cnt,
                                                gcnG + DD, gcnBb + DD, H2, DD, 0,
                                                S1, P);
    // 6. T = relu([S1|P2]@mW1^T + mB1); G2 = H2@gcnW2^T + b2
    gemm_step6<<<dgrid, blk, 0, stream>>>(S1, P, H2, wbuf, mB + DD, gcnB + 2 * DD,
                                          T, G);
    // 7. outL = propLN(G2, resid=H2); S2 = LN(T + S1)
    prop_addln_kernel<<<rgrid, blk, 0, stream>>>(G, H2, dinv, kept, neigh,
                                                 gcnG + 2 * DD, gcnBb + 2 * DD,
                                                 out, 2 * DD, 0,
                                                 T, S1, sg, sb, S2);
    // 8. P3 = pool(S2)
    pool_kernel<<<rgrid, blk, 0, stream>>>(S2, neigh, cnt, P);
    // 9. T = relu([S2|P3]@mW2^T + mB2)
    gemm2_mfma<<<ggrid, blk, 0, stream>>>(S2, P, wbuf, mB + 2 * DD, T);
    // 10. outR = LN(T + S2)
    add_ln_kernel<<<rgrid, blk, 0, stream>>>(T, S2, sg + DD, sb + DD,
                                             out, 2 * DD, DD);
}